// Round 1
// baseline (1192.983 us; speedup 1.0000x reference)
//
#include <hip/hip_runtime.h>

#define DD   1024
#define NHH  16
#define HDD  64
#define BB   2
#define SS   2048
#define MT   (BB*SS)   // 4096
#define BL   16
#define BN   32

typedef __attribute__((ext_vector_type(8))) __bf16 bf16x8;
typedef __attribute__((ext_vector_type(4))) float  floatx4;
typedef __attribute__((ext_vector_type(4))) short  shortx4;

static __device__ __forceinline__ short bf16_of(float f) {
    unsigned u = __builtin_bit_cast(unsigned, f);
    u = (u + 0x7fffu + ((u >> 16) & 1u)) >> 16;
    return (short)u;
}

// ---------------- cast fp32 -> bf16 (vectorized x4) ----------------
__global__ void cast_f32_to_bf16(const float* __restrict__ in,
                                 short* __restrict__ out, int n4) {
    int i = blockIdx.x * blockDim.x + threadIdx.x;
    if (i >= n4) return;
    floatx4 f = ((const floatx4*)in)[i];
    shortx4 o;
    o[0] = bf16_of(f[0]); o[1] = bf16_of(f[1]);
    o[2] = bf16_of(f[2]); o[3] = bf16_of(f[3]);
    ((shortx4*)out)[i] = o;
}

// ---------------- transpose + cast weight: Wt[o][i] = W[i][o] ----------------
__global__ void transpose_cast_w(const float* __restrict__ W,
                                 short* __restrict__ Wt) {
    __shared__ float tile[32][33];
    int tx = threadIdx.x & 31, ty = threadIdx.x >> 5;   // 256 thr: ty 0..7
    int o0 = blockIdx.x * 32, i0 = blockIdx.y * 32;
#pragma unroll
    for (int r = 0; r < 32; r += 8)
        tile[ty + r][tx] = W[(size_t)(i0 + ty + r) * DD + o0 + tx];
    __syncthreads();
#pragma unroll
    for (int r = 0; r < 32; r += 8)
        Wt[(size_t)(o0 + ty + r) * DD + i0 + tx] = bf16_of(tile[tx][ty + r]);
}

// ---------------- projection GEMM: Y = X @ W + b, scatter to per-head layout --
// X [4096][1024] bf16, Wt [out][in] bf16.  vmode 0: out[b][h][l][d] (q,k)
//                                          vmode 1: out[b][h][d][l] (v transposed)
__global__ __launch_bounds__(256) void gemm_proj(
    const short* __restrict__ X, const short* __restrict__ Wt,
    const float* __restrict__ bias, short* __restrict__ out, int vmode) {
    int wave = threadIdx.x >> 6, lane = threadIdx.x & 63;
    int quad = lane >> 4, lr = lane & 15;
    int m0 = blockIdx.x * 64 + (wave >> 1) * 32;
    int n0 = blockIdx.y * 64 + (wave & 1) * 32;
    floatx4 acc[2][2] = {};
    for (int k0 = 0; k0 < DD; k0 += 32) {
        bf16x8 a[2], bfr[2];
#pragma unroll
        for (int mb = 0; mb < 2; mb++)
            a[mb] = *(const bf16x8*)(X + (size_t)(m0 + mb*16 + lr) * DD + k0 + quad*8);
#pragma unroll
        for (int nb = 0; nb < 2; nb++)
            bfr[nb] = *(const bf16x8*)(Wt + (size_t)(n0 + nb*16 + lr) * DD + k0 + quad*8);
#pragma unroll
        for (int mb = 0; mb < 2; mb++)
#pragma unroll
            for (int nb = 0; nb < 2; nb++)
                acc[mb][nb] = __builtin_amdgcn_mfma_f32_16x16x32_bf16(
                    a[mb], bfr[nb], acc[mb][nb], 0, 0, 0);
    }
#pragma unroll
    for (int mb = 0; mb < 2; mb++)
#pragma unroll
    for (int nb = 0; nb < 2; nb++)
#pragma unroll
    for (int r = 0; r < 4; r++) {
        int m = m0 + mb*16 + quad*4 + r;
        int n = n0 + nb*16 + lr;
        float y = acc[mb][nb][r] + bias[n];
        int b = m >> 11, l = m & (SS - 1);
        int h = n & (NHH - 1), d = n >> 4;
        size_t idx;
        if (vmode == 0) idx = (((size_t)(b*NHH + h) * SS) + l) * HDD + d;
        else            idx = (((size_t)(b*NHH + h) * HDD) + d) * SS + l;
        out[idx] = bf16_of(y);
    }
}

// ---------------- output GEMM: out = X @ Wo + bo (fp32 out) ----------------
__global__ __launch_bounds__(256) void gemm_outp(
    const short* __restrict__ X, const short* __restrict__ Wt,
    const float* __restrict__ bias, float* __restrict__ out) {
    int wave = threadIdx.x >> 6, lane = threadIdx.x & 63;
    int quad = lane >> 4, lr = lane & 15;
    int m0 = blockIdx.x * 64 + (wave >> 1) * 32;
    int n0 = blockIdx.y * 64 + (wave & 1) * 32;
    floatx4 acc[2][2] = {};
    for (int k0 = 0; k0 < DD; k0 += 32) {
        bf16x8 a[2], bfr[2];
#pragma unroll
        for (int mb = 0; mb < 2; mb++)
            a[mb] = *(const bf16x8*)(X + (size_t)(m0 + mb*16 + lr) * DD + k0 + quad*8);
#pragma unroll
        for (int nb = 0; nb < 2; nb++)
            bfr[nb] = *(const bf16x8*)(Wt + (size_t)(n0 + nb*16 + lr) * DD + k0 + quad*8);
#pragma unroll
        for (int mb = 0; mb < 2; mb++)
#pragma unroll
            for (int nb = 0; nb < 2; nb++)
                acc[mb][nb] = __builtin_amdgcn_mfma_f32_16x16x32_bf16(
                    a[mb], bfr[nb], acc[mb][nb], 0, 0, 0);
    }
#pragma unroll
    for (int mb = 0; mb < 2; mb++)
#pragma unroll
    for (int nb = 0; nb < 2; nb++)
#pragma unroll
    for (int r = 0; r < 4; r++) {
        int m = m0 + mb*16 + quad*4 + r;
        int n = n0 + nb*16 + lr;
        out[(size_t)m * DD + n] = acc[mb][nb][r] + bias[n];
    }
}

// ---------------- fused attention: scores -> softmax(over h) -> probs + P@V --
// block = 1024 thr = 16 waves; wave w handles head h=w. Grid = B * S/BL.
// LDS layout: sm[h*528 + l*33 + n]  (stride-33 padding)
__global__ __launch_bounds__(1024) void attn_fused(
    const short* __restrict__ qws, const short* __restrict__ kws,
    const short* __restrict__ vtws, float* __restrict__ probs,
    short* __restrict__ aout) {
    __shared__ float sm[NHH * 528];
    int h = threadIdx.x >> 6, lane = threadIdx.x & 63;
    int quad = lane >> 4, lr = lane & 15;
    int b  = blockIdx.x >> 7;
    int l0 = (blockIdx.x & 127) * BL;

    const short* qh = qws  + ((size_t)(b*NHH + h) * SS) * HDD;
    const short* kh = kws  + ((size_t)(b*NHH + h) * SS) * HDD;
    const short* vh = vtws + ((size_t)(b*NHH + h) * HDD) * SS;

    bf16x8 aq0 = *(const bf16x8*)(qh + (size_t)(l0 + lr) * HDD + quad*8);
    bf16x8 aq1 = *(const bf16x8*)(qh + (size_t)(l0 + lr) * HDD + 32 + quad*8);

    floatx4 acco[4] = {};

    for (int nt = 0; nt < SS / BN; nt++) {
        int n0 = nt * BN;
        // ---- scores for this head's 16x32 tile ----
#pragma unroll
        for (int nb = 0; nb < 2; nb++) {
            bf16x8 bk0 = *(const bf16x8*)(kh + (size_t)(n0 + nb*16 + lr) * HDD + quad*8);
            bf16x8 bk1 = *(const bf16x8*)(kh + (size_t)(n0 + nb*16 + lr) * HDD + 32 + quad*8);
            floatx4 s = {};
            s = __builtin_amdgcn_mfma_f32_16x16x32_bf16(aq0, bk0, s, 0, 0, 0);
            s = __builtin_amdgcn_mfma_f32_16x16x32_bf16(aq1, bk1, s, 0, 0, 0);
#pragma unroll
            for (int r = 0; r < 4; r++) {
                int ll = quad*4 + r, nn = nb*16 + lr;
                sm[h*528 + ll*33 + nn] = s[r] * 0.125f;
            }
        }
        __syncthreads();
        // ---- softmax over h (16 values) for each of 512 (l,n) pairs ----
        if (threadIdx.x < BL*BN) {
            int ll = threadIdx.x >> 5, nn = threadIdx.x & 31;
            int base = ll*33 + nn;
            float p[16];
            float mx = -1e30f;
#pragma unroll
            for (int i = 0; i < 16; i++) { p[i] = sm[i*528 + base]; mx = fmaxf(mx, p[i]); }
            float sum = 0.f;
#pragma unroll
            for (int i = 0; i < 16; i++) { p[i] = __expf(p[i] - mx); sum += p[i]; }
            float inv = 1.f / sum;
            float* gp = probs + ((size_t)(b*SS + l0 + ll) * SS + n0 + nn) * NHH;
#pragma unroll
            for (int i = 0; i < 16; i++) { p[i] *= inv; sm[i*528 + base] = p[i]; }
#pragma unroll
            for (int i = 0; i < 4; i++) {
                floatx4 t; t[0]=p[4*i]; t[1]=p[4*i+1]; t[2]=p[4*i+2]; t[3]=p[4*i+3];
                ((floatx4*)gp)[i] = t;
            }
        }
        __syncthreads();
        // ---- P @ V accumulate: A-frag = P[l=lr][n=quad*8+j] ----
        union { short s[8]; bf16x8 v; } apu;
#pragma unroll
        for (int j = 0; j < 8; j++)
            apu.s[j] = bf16_of(sm[h*528 + lr*33 + quad*8 + j]);
#pragma unroll
        for (int db = 0; db < 4; db++) {
            bf16x8 bv = *(const bf16x8*)(vh + (size_t)(db*16 + lr) * SS + n0 + quad*8);
            acco[db] = __builtin_amdgcn_mfma_f32_16x16x32_bf16(apu.v, bv, acco[db], 0, 0, 0);
        }
        __syncthreads();
    }
    // write attn output in [m][c] layout, c = d*16 + h (bf16 for final GEMM)
#pragma unroll
    for (int db = 0; db < 4; db++)
#pragma unroll
    for (int r = 0; r < 4; r++) {
        int ll = quad*4 + r, d = db*16 + lr;
        aout[(size_t)(b*SS + l0 + ll) * DD + d*NHH + h] = bf16_of(acco[db][r]);
    }
}

extern "C" void kernel_launch(void* const* d_in, const int* in_sizes, int n_in,
                              void* d_out, int out_size, void* d_ws, size_t ws_size,
                              hipStream_t stream) {
    const float* query = (const float*)d_in[0];
    const float* key_  = (const float*)d_in[1];
    const float* value = (const float*)d_in[2];
    const float* Wq = (const float*)d_in[3];
    const float* bq = (const float*)d_in[4];
    const float* Wk = (const float*)d_in[5];
    const float* bk = (const float*)d_in[6];
    const float* Wv = (const float*)d_in[7];
    const float* bv = (const float*)d_in[8];
    const float* Wo = (const float*)d_in[9];
    const float* bo = (const float*)d_in[10];

    float* out   = (float*)d_out;
    float* probs = out + (size_t)MT * DD;

    const size_t SZ_X = (size_t)MT * DD;   // 4,194,304
    const size_t SZ_W = (size_t)DD * DD;   // 1,048,576
    short* ws   = (short*)d_ws;
    short* xq   = ws;
    short* xk   = xq + SZ_X;
    short* xv   = xk + SZ_X;
    short* wtq  = xv + SZ_X;
    short* wtk  = wtq + SZ_W;
    short* wtv  = wtk + SZ_W;
    short* wto  = wtv + SZ_W;
    short* qws  = wto + SZ_W;
    short* kws  = qws + SZ_X;
    short* vtws = kws + SZ_X;
    short* aout = vtws + SZ_X;             // total ~67 MB

    int n4 = (int)(SZ_X / 4);
    cast_f32_to_bf16<<<n4 / 256, 256, 0, stream>>>(query, xq, n4);
    cast_f32_to_bf16<<<n4 / 256, 256, 0, stream>>>(key_,  xk, n4);
    cast_f32_to_bf16<<<n4 / 256, 256, 0, stream>>>(value, xv, n4);

    transpose_cast_w<<<dim3(32, 32), 256, 0, stream>>>(Wq, wtq);
    transpose_cast_w<<<dim3(32, 32), 256, 0, stream>>>(Wk, wtk);
    transpose_cast_w<<<dim3(32, 32), 256, 0, stream>>>(Wv, wtv);
    transpose_cast_w<<<dim3(32, 32), 256, 0, stream>>>(Wo, wto);

    gemm_proj<<<dim3(64, 16), 256, 0, stream>>>(xq, wtq, bq, qws, 0);
    gemm_proj<<<dim3(64, 16), 256, 0, stream>>>(xk, wtk, bk, kws, 0);
    gemm_proj<<<dim3(64, 16), 256, 0, stream>>>(xv, wtv, bv, vtws, 1);

    attn_fused<<<BB * (SS / BL), 1024, 0, stream>>>(qws, kws, vtws, probs, aout);

    gemm_outp<<<dim3(64, 16), 256, 0, stream>>>(aout, wto, bo, out);
}

// Round 2
// 1062.297 us; speedup vs baseline: 1.1230x; 1.1230x over previous
//
#include <hip/hip_runtime.h>

#define DD   1024
#define NHH  16
#define HDD  64
#define BB   2
#define SS   2048
#define MT   (BB*SS)   // 4096
#define BL   16
#define BN   32
#define NSPLIT 2

typedef __attribute__((ext_vector_type(8))) __bf16 bf16x8;
typedef __attribute__((ext_vector_type(4))) float  floatx4;
typedef __attribute__((ext_vector_type(4))) short  shortx4;

static __device__ __forceinline__ short bf16_of(float f) {
    unsigned u = __builtin_bit_cast(unsigned, f);
    u = (u + 0x7fffu + ((u >> 16) & 1u)) >> 16;
    return (short)u;
}

static __device__ __forceinline__ void async_copy16(const short* g, short* l) {
    __builtin_amdgcn_global_load_lds(
        (const __attribute__((address_space(1))) unsigned int*)g,
        (__attribute__((address_space(3))) unsigned int*)l,
        16, 0, 0);
}

// ---------------- cast fp32 -> bf16 (vectorized x4) ----------------
__global__ void cast_f32_to_bf16(const float* __restrict__ in,
                                 short* __restrict__ out, int n4) {
    int i = blockIdx.x * blockDim.x + threadIdx.x;
    if (i >= n4) return;
    floatx4 f = ((const floatx4*)in)[i];
    shortx4 o;
    o[0] = bf16_of(f[0]); o[1] = bf16_of(f[1]);
    o[2] = bf16_of(f[2]); o[3] = bf16_of(f[3]);
    ((shortx4*)out)[i] = o;
}

// ---------------- transpose + cast weight: Wt[o][i] = W[i][o] ----------------
__global__ void transpose_cast_w(const float* __restrict__ W,
                                 short* __restrict__ Wt) {
    __shared__ float tile[32][33];
    int tx = threadIdx.x & 31, ty = threadIdx.x >> 5;
    int o0 = blockIdx.x * 32, i0 = blockIdx.y * 32;
#pragma unroll
    for (int r = 0; r < 32; r += 8)
        tile[ty + r][tx] = W[(size_t)(i0 + ty + r) * DD + o0 + tx];
    __syncthreads();
#pragma unroll
    for (int r = 0; r < 32; r += 8)
        Wt[(size_t)(o0 + ty + r) * DD + i0 + tx] = bf16_of(tile[tx][ty + r]);
}

// ---------------- tiled GEMM (m97-style): Y = X @ Wt^T + b ----------------
// X [4096][1024] bf16 row-major, Wt [n][k] bf16. BM=128 BN=64 BK=32, 256 thr.
// mode 0: scatter bf16 out[b][h][l][d]   (q,k)
// mode 1: scatter bf16 out[b][h][d][l]   (v transposed)
// mode 2: fp32 out[m][n]                 (final projection)
__global__ __launch_bounds__(256) void gemm_tiled(
    const short* __restrict__ X, const short* __restrict__ Wt,
    const float* __restrict__ bias, void* __restrict__ out, int mode) {
    __shared__ short As[128 * 32];
    __shared__ short Bs[64 * 32];
    int t = threadIdx.x;
    int wave = t >> 6, lane = t & 63;
    int quad = lane >> 4, lr = lane & 15;
    int wm = wave & 1, wn = wave >> 1;
    int m0 = blockIdx.x * 128, n0 = blockIdx.y * 64;

    int arow = t >> 2, acol = (t & 3) * 8;   // within-tile load coords
    floatx4 acc[4][2] = {};

    for (int k0 = 0; k0 < DD; k0 += 32) {
        // stage A (2 passes of 4 KB) and B (1 pass) via async global->LDS
        async_copy16(X + (size_t)(m0 + arow) * DD + k0 + acol,       As + t * 8);
        async_copy16(X + (size_t)(m0 + 64 + arow) * DD + k0 + acol,  As + 2048 + t * 8);
        async_copy16(Wt + (size_t)(n0 + arow) * DD + k0 + acol,      Bs + t * 8);
        __syncthreads();
        bf16x8 a[4], bb[2];
#pragma unroll
        for (int mi = 0; mi < 4; mi++)
            a[mi] = *(const bf16x8*)(As + (wm * 64 + mi * 16 + lr) * 32 + quad * 8);
#pragma unroll
        for (int ni = 0; ni < 2; ni++)
            bb[ni] = *(const bf16x8*)(Bs + (wn * 32 + ni * 16 + lr) * 32 + quad * 8);
#pragma unroll
        for (int mi = 0; mi < 4; mi++)
#pragma unroll
            for (int ni = 0; ni < 2; ni++)
                acc[mi][ni] = __builtin_amdgcn_mfma_f32_16x16x32_bf16(
                    a[mi], bb[ni], acc[mi][ni], 0, 0, 0);
        __syncthreads();
    }

#pragma unroll
    for (int mi = 0; mi < 4; mi++)
#pragma unroll
    for (int ni = 0; ni < 2; ni++)
#pragma unroll
    for (int r = 0; r < 4; r++) {
        int m = m0 + wm * 64 + mi * 16 + quad * 4 + r;
        int n = n0 + wn * 32 + ni * 16 + lr;
        float y = acc[mi][ni][r] + bias[n];
        if (mode == 2) {
            ((float*)out)[(size_t)m * DD + n] = y;
        } else {
            int b = m >> 11, l = m & (SS - 1);
            int h = n & (NHH - 1), d = n >> 4;
            size_t idx;
            if (mode == 0) idx = (((size_t)(b * NHH + h) * SS) + l) * HDD + d;
            else           idx = (((size_t)(b * NHH + h) * HDD) + d) * SS + l;
            ((short*)out)[idx] = bf16_of(y);
        }
    }
}

// ---------------- fused attention: scores -> softmax(over h) -> probs + P@V --
// block = 1024 thr = 16 waves; wave w = head h. Grid = B * S/BL * NSPLIT.
// Each block handles n-chunk of SS/NSPLIT positions; partial P@V to ws fp32.
__global__ __launch_bounds__(1024) void attn_fused(
    const short* __restrict__ qws, const short* __restrict__ kws,
    const short* __restrict__ vtws, float* __restrict__ probs,
    float* __restrict__ partial) {
    __shared__ float sm[NHH * 528];
    int h = threadIdx.x >> 6, lane = threadIdx.x & 63;
    int quad = lane >> 4, lr = lane & 15;
    int c    = blockIdx.x & (NSPLIT - 1);
    int l0   = ((blockIdx.x >> 1) & 127) * BL;
    int b    = blockIdx.x >> 8;

    const short* qh = qws  + ((size_t)(b * NHH + h) * SS) * HDD;
    const short* kh = kws  + ((size_t)(b * NHH + h) * SS) * HDD;
    const short* vh = vtws + ((size_t)(b * NHH + h) * HDD) * SS;

    bf16x8 aq0 = *(const bf16x8*)(qh + (size_t)(l0 + lr) * HDD + quad * 8);
    bf16x8 aq1 = *(const bf16x8*)(qh + (size_t)(l0 + lr) * HDD + 32 + quad * 8);

    floatx4 acco[4] = {};
    const int NT = (SS / BN) / NSPLIT;          // 32 tiles per block

    for (int nt = c * NT; nt < (c + 1) * NT; nt++) {
        int n0 = nt * BN;
#pragma unroll
        for (int nb = 0; nb < 2; nb++) {
            bf16x8 bk0 = *(const bf16x8*)(kh + (size_t)(n0 + nb * 16 + lr) * HDD + quad * 8);
            bf16x8 bk1 = *(const bf16x8*)(kh + (size_t)(n0 + nb * 16 + lr) * HDD + 32 + quad * 8);
            floatx4 s = {};
            s = __builtin_amdgcn_mfma_f32_16x16x32_bf16(aq0, bk0, s, 0, 0, 0);
            s = __builtin_amdgcn_mfma_f32_16x16x32_bf16(aq1, bk1, s, 0, 0, 0);
#pragma unroll
            for (int r = 0; r < 4; r++) {
                int ll = quad * 4 + r, nn = nb * 16 + lr;
                sm[h * 528 + ll * 33 + nn] = s[r] * 0.125f;
            }
        }
        __syncthreads();
        if (threadIdx.x < BL * BN) {
            int ll = threadIdx.x >> 5, nn = threadIdx.x & 31;
            int base = ll * 33 + nn;
            float p[16];
            float mx = -1e30f;
#pragma unroll
            for (int i = 0; i < 16; i++) { p[i] = sm[i * 528 + base]; mx = fmaxf(mx, p[i]); }
            float sum = 0.f;
#pragma unroll
            for (int i = 0; i < 16; i++) { p[i] = __expf(p[i] - mx); sum += p[i]; }
            float inv = 1.f / sum;
            float* gp = probs + ((size_t)(b * SS + l0 + ll) * SS + n0 + nn) * NHH;
#pragma unroll
            for (int i = 0; i < 16; i++) { p[i] *= inv; sm[i * 528 + base] = p[i]; }
#pragma unroll
            for (int i = 0; i < 4; i++) {
                floatx4 tv; tv[0]=p[4*i]; tv[1]=p[4*i+1]; tv[2]=p[4*i+2]; tv[3]=p[4*i+3];
                ((floatx4*)gp)[i] = tv;
            }
        }
        __syncthreads();
        union { short s[8]; bf16x8 v; } apu;
#pragma unroll
        for (int j = 0; j < 8; j++)
            apu.s[j] = bf16_of(sm[h * 528 + lr * 33 + quad * 8 + j]);
#pragma unroll
        for (int db = 0; db < 4; db++) {
            bf16x8 bv = *(const bf16x8*)(vh + (size_t)(db * 16 + lr) * SS + n0 + quad * 8);
            acco[db] = __builtin_amdgcn_mfma_f32_16x16x32_bf16(apu.v, bv, acco[db], 0, 0, 0);
        }
        __syncthreads();
    }

    // Epilogue: stage partial [l][c'] (c' = d*16+h) in LDS, write coalesced fp32
    float* pc = partial + (size_t)c * MT * DD;
#pragma unroll
    for (int half = 0; half < 2; half++) {
#pragma unroll
        for (int db2 = 0; db2 < 2; db2++) {
            int db = half * 2 + db2;
#pragma unroll
            for (int r = 0; r < 4; r++) {
                int ll = quad * 4 + r;
                int dloc = db2 * 16 + lr;
                sm[ll * 528 + dloc * 16 + h] = acco[db][r];
            }
        }
        __syncthreads();
        int l  = threadIdx.x >> 6;
        int c0 = (threadIdx.x & 63) * 8;
        float* dst = pc + (size_t)(b * SS + l0 + l) * DD + half * 512 + c0;
        const float* srcp = &sm[l * 528 + c0];
        ((floatx4*)dst)[0] = ((const floatx4*)srcp)[0];
        ((floatx4*)dst)[1] = ((const floatx4*)srcp)[1];
        __syncthreads();
    }
}

// ---------------- reduce NSPLIT partials -> bf16 aout [m][c] ----------------
__global__ void reduce_partials(const float* __restrict__ pa,
                                short* __restrict__ aout) {
    size_t i = (size_t)blockIdx.x * blockDim.x + threadIdx.x;   // one floatx4
    floatx4 a = ((const floatx4*)pa)[i];
    floatx4 b = ((const floatx4*)pa)[i + (size_t)MT * DD / 4];
    shortx4 o;
    o[0] = bf16_of(a[0] + b[0]); o[1] = bf16_of(a[1] + b[1]);
    o[2] = bf16_of(a[2] + b[2]); o[3] = bf16_of(a[3] + b[3]);
    ((shortx4*)aout)[i] = o;
}

extern "C" void kernel_launch(void* const* d_in, const int* in_sizes, int n_in,
                              void* d_out, int out_size, void* d_ws, size_t ws_size,
                              hipStream_t stream) {
    const float* query = (const float*)d_in[0];
    const float* key_  = (const float*)d_in[1];
    const float* value = (const float*)d_in[2];
    const float* Wq = (const float*)d_in[3];
    const float* bq = (const float*)d_in[4];
    const float* Wk = (const float*)d_in[5];
    const float* bk = (const float*)d_in[6];
    const float* Wv = (const float*)d_in[7];
    const float* bv = (const float*)d_in[8];
    const float* Wo = (const float*)d_in[9];
    const float* bo = (const float*)d_in[10];

    float* out   = (float*)d_out;
    float* probs = out + (size_t)MT * DD;

    const size_t SZ_X = (size_t)MT * DD;   // 4 Mi elements
    const size_t SZ_W = (size_t)DD * DD;   // 1 Mi elements
    short* ws   = (short*)d_ws;
    // persistent-through-attn region (34 MB)
    short* wto  = ws;
    short* qws  = wto + SZ_W;
    short* kws  = qws + SZ_X;
    short* vtws = kws + SZ_X;
    short* aout = vtws + SZ_X;
    // scratch region (reused): xq..wtv (30 MB) then overlapped by partial (32 MB)
    short* xq   = aout + SZ_X;
    short* xk   = xq + SZ_X;
    short* xv   = xk + SZ_X;
    short* wtq  = xv + SZ_X;
    short* wtk  = wtq + SZ_W;
    short* wtv  = wtk + SZ_W;
    float* partial = (float*)xq;           // 2 * 16 MB, live only after projections

    int n4 = (int)(SZ_X / 4);
    cast_f32_to_bf16<<<n4 / 256, 256, 0, stream>>>(query, xq, n4);
    cast_f32_to_bf16<<<n4 / 256, 256, 0, stream>>>(key_,  xk, n4);
    cast_f32_to_bf16<<<n4 / 256, 256, 0, stream>>>(value, xv, n4);

    transpose_cast_w<<<dim3(32, 32), 256, 0, stream>>>(Wq, wtq);
    transpose_cast_w<<<dim3(32, 32), 256, 0, stream>>>(Wk, wtk);
    transpose_cast_w<<<dim3(32, 32), 256, 0, stream>>>(Wv, wtv);
    transpose_cast_w<<<dim3(32, 32), 256, 0, stream>>>(Wo, wto);

    gemm_tiled<<<dim3(32, 16), 256, 0, stream>>>(xq, wtq, bq, qws, 0);
    gemm_tiled<<<dim3(32, 16), 256, 0, stream>>>(xk, wtk, bk, kws, 0);
    gemm_tiled<<<dim3(32, 16), 256, 0, stream>>>(xv, wtv, bv, vtws, 1);

    attn_fused<<<BB * (SS / BL) * NSPLIT, 1024, 0, stream>>>(qws, kws, vtws, probs, partial);

    reduce_partials<<<(int)(SZ_X / 4 / 256), 256, 0, stream>>>(partial, aout);

    gemm_tiled<<<dim3(32, 16), 256, 0, stream>>>(aout, wto, bo, out, 2);
}